// Round 1
// 183.829 us; speedup vs baseline: 1.0405x; 1.0405x over previous
//
#include <hip/hip_runtime.h>
#include <hip/hip_bf16.h>
#include <math.h>

#define EMBED 1024
#define HDIM  64
#define BATCH 4
#define SEQ   2048

typedef __attribute__((ext_vector_type(8))) short short8;
typedef __attribute__((ext_vector_type(4))) float f32x4;
typedef unsigned int u32;
typedef unsigned short u16;

static __device__ __forceinline__ u16 f2bf(float f) {
    union { float f; u32 u; } v; v.f = f;
    u32 r = v.u + 0x7fffu + ((v.u >> 16) & 1u);  // round-to-nearest-even
    return (u16)(r >> 16);
}

// async global->LDS, 16B per lane. LDS dest must equal uniform_base + lane*16.
static __device__ __forceinline__ void gload_lds16(const u16* g, u16* l) {
    __builtin_amdgcn_global_load_lds(
        (const __attribute__((address_space(1))) u32*)g,
        (__attribute__((address_space(3))) u32*)l, 16, 0, 0);
}

// ---------------------------------------------------------------------------
// K0: WqT[d][e] = bf16(Wq[e][d]), WkT likewise. grid (16,2) x 256.
// ---------------------------------------------------------------------------
__global__ __launch_bounds__(256) void wt_kernel(
    const float* __restrict__ Wq, const float* __restrict__ Wk,
    u16* __restrict__ WqT, u16* __restrict__ WkT)
{
    __shared__ float tile[64][65];
    const float* W = blockIdx.y ? Wk : Wq;
    u16* WT = blockIdx.y ? WkT : WqT;
    int e0 = blockIdx.x * 64;
    int t = threadIdx.x, c = t & 63, r4 = t >> 6;
    for (int r = r4; r < 64; r += 4)
        tile[r][c] = W[(size_t)(e0 + r) * HDIM + c];   // tile[e-e0][d]
    __syncthreads();
    for (int d = r4; d < 64; d += 4)
        WT[(size_t)d * EMBED + e0 + c] = f2bf(tile[c][d]);
}

// ---------------------------------------------------------------------------
// K1: proj only (transpose removed). Q = 0.125*(h*Wq+bq), K = h*Wk+bk.
// grid 512 (B * S/16), 256 thr, 16 s-rows/block, EC=128 per iter:
// 8 iters, 8 barriers, 8 MFMA + 4 ds_read_b128 per wave per iter.
// Double-buffered LDS; h and W-frags prefetched 1 iter ahead.
// ---------------------------------------------------------------------------
__global__ __launch_bounds__(256) void proj_kernel(
    const float* __restrict__ h, const u16* __restrict__ WqT, const u16* __restrict__ WkT,
    const float* __restrict__ bq, const float* __restrict__ bk,
    u16* __restrict__ Qbf, u16* __restrict__ Kbf)
{
    __shared__ u16 hs[2][16][136];   // 128 + 8 pad
    int b = blockIdx.x >> 7, s0 = (blockIdx.x & 127) * 16;
    int t = threadIdx.x, lane = t & 63, w = t >> 6;
    int l15 = lane & 15, quad = lane >> 4;
    int pj = w >> 1, nh = (w & 1) * 32;
    const float* hb = h + ((size_t)b * SEQ + s0) * EMBED;
    const u16* Wp = pj ? WkT : WqT;
    int r = t >> 4, c4 = (t & 15) * 4;   // staging: 16 rows x (16 f32x4 x 2 halves)

    f32x4 pre0 = *(const f32x4*)(hb + (size_t)r * EMBED + c4);
    f32x4 pre1 = *(const f32x4*)(hb + (size_t)r * EMBED + 64 + c4);
    f32x4 accA[2], accB[2];
    accA[0] = accA[1] = accB[0] = accB[1] = (f32x4){0.f, 0.f, 0.f, 0.f};

    const u16* Wrow0 = Wp + (size_t)(nh + l15) * EMBED;
    const u16* Wrow1 = Wp + (size_t)(nh + 16 + l15) * EMBED;

    short8 cw[8];
#pragma unroll
    for (int i = 0; i < 4; i++) {
        cw[i]     = *(const short8*)(Wrow0 + i * 32 + quad * 8);
        cw[4 + i] = *(const short8*)(Wrow1 + i * 32 + quad * 8);
    }

    for (int it = 0; it < 8; ++it) {
        int ec = it * 128, buf = it & 1;
        uint2 pk;
        pk.x = (u32)f2bf(pre0[0]) | ((u32)f2bf(pre0[1]) << 16);
        pk.y = (u32)f2bf(pre0[2]) | ((u32)f2bf(pre0[3]) << 16);
        *(uint2*)&hs[buf][r][c4] = pk;
        pk.x = (u32)f2bf(pre1[0]) | ((u32)f2bf(pre1[1]) << 16);
        pk.y = (u32)f2bf(pre1[2]) | ((u32)f2bf(pre1[3]) << 16);
        *(uint2*)&hs[buf][r][64 + c4] = pk;
        __syncthreads();

        if (it + 1 < 8) {
            pre0 = *(const f32x4*)(hb + (size_t)r * EMBED + ec + 128 + c4);
            pre1 = *(const f32x4*)(hb + (size_t)r * EMBED + ec + 192 + c4);
        }
        short8 nw[8];
#pragma unroll
        for (int i = 0; i < 8; i++) nw[i] = cw[i];
        if (it + 1 < 8) {
#pragma unroll
            for (int i = 0; i < 4; i++) {
                nw[i]     = *(const short8*)(Wrow0 + ec + 128 + i * 32 + quad * 8);
                nw[4 + i] = *(const short8*)(Wrow1 + ec + 128 + i * 32 + quad * 8);
            }
        }

        short8 a0 = *(const short8*)&hs[buf][l15][quad * 8];
        short8 a1 = *(const short8*)&hs[buf][l15][32 + quad * 8];
        short8 a2 = *(const short8*)&hs[buf][l15][64 + quad * 8];
        short8 a3 = *(const short8*)&hs[buf][l15][96 + quad * 8];
        // dependent accumulator reuses 4 apart
        accA[0] = __builtin_amdgcn_mfma_f32_16x16x32_bf16(a0, cw[0], accA[0], 0, 0, 0);
        accA[1] = __builtin_amdgcn_mfma_f32_16x16x32_bf16(a0, cw[4], accA[1], 0, 0, 0);
        accB[0] = __builtin_amdgcn_mfma_f32_16x16x32_bf16(a1, cw[1], accB[0], 0, 0, 0);
        accB[1] = __builtin_amdgcn_mfma_f32_16x16x32_bf16(a1, cw[5], accB[1], 0, 0, 0);
        accA[0] = __builtin_amdgcn_mfma_f32_16x16x32_bf16(a2, cw[2], accA[0], 0, 0, 0);
        accA[1] = __builtin_amdgcn_mfma_f32_16x16x32_bf16(a2, cw[6], accA[1], 0, 0, 0);
        accB[0] = __builtin_amdgcn_mfma_f32_16x16x32_bf16(a3, cw[3], accB[0], 0, 0, 0);
        accB[1] = __builtin_amdgcn_mfma_f32_16x16x32_bf16(a3, cw[7], accB[1], 0, 0, 0);
#pragma unroll
        for (int i = 0; i < 8; i++) cw[i] = nw[i];
    }

    const float* bias = pj ? bk : bq;
    float scale = pj ? 1.0f : 0.125f;
    u16* outp = pj ? Kbf : Qbf;
    float bv0 = bias[nh + l15], bv1 = bias[nh + 16 + l15];
#pragma unroll
    for (int rr = 0; rr < 4; rr++) {
        size_t row = (size_t)b * SEQ + s0 + quad * 4 + rr;
        outp[row * HDIM + nh + l15]      = f2bf((accA[0][rr] + accB[0][rr] + bv0) * scale);
        outp[row * HDIM + nh + 16 + l15] = f2bf((accA[1][rr] + accB[1][rr] + bv1) * scale);
    }
}

// ---------------------------------------------------------------------------
// K2: stats+weights SINGLE PASS. Block owns 16 k (k0) x all q; wave w owns
// q in [w*512,+512). K-frags loop-invariant. Per 32-q iter: 4 MFMA ->
// exp -> packed 8B stores of UNNORMALIZED exp(S) to Wmat + accumulate l.
// Ends writing invl[k] = 1/l[k]. grid (S/16, B) x 256.
// ---------------------------------------------------------------------------
__global__ __launch_bounds__(256) void sw_kernel(
    const u16* __restrict__ Qbf, const u16* __restrict__ Kbf,
    u16* __restrict__ Wmat, float* __restrict__ invl)
{
    __shared__ float sl[4][16];
    int b = blockIdx.y;
    int k0 = blockIdx.x * 16;
    int t = threadIdx.x, lane = t & 63, w = t >> 6;
    int l15 = lane & 15, quad = lane >> 4;
    const u16* Qb = Qbf + (size_t)b * SEQ * HDIM;
    const u16* Kb = Kbf + (size_t)b * SEQ * HDIM;
    u16* Wb = Wmat + (size_t)b * SEQ * SEQ;
    short8 kf0 = *(const short8*)(Kb + (size_t)(k0 + l15) * HDIM + quad * 8);
    short8 kf1 = *(const short8*)(Kb + (size_t)(k0 + l15) * HDIM + 32 + quad * 8);
    f32x4 lacc = {0.f, 0.f, 0.f, 0.f};
    int qs = w * 512;
    const u16* qpa = Qb + (size_t)(qs + l15) * HDIM;
    const u16* qpb = Qb + (size_t)(qs + 16 + l15) * HDIM;
    short8 cf0a = *(const short8*)(qpa + quad * 8);
    short8 cf1a = *(const short8*)(qpa + 32 + quad * 8);
    short8 cf0b = *(const short8*)(qpb + quad * 8);
    short8 cf1b = *(const short8*)(qpb + 32 + quad * 8);

    for (int q0 = qs; q0 < qs + 512; q0 += 32) {
        short8 nf0a = cf0a, nf1a = cf1a, nf0b = cf0b, nf1b = cf1b;
        if (q0 + 32 < qs + 512) {
            const u16* na = Qb + (size_t)(q0 + 32 + l15) * HDIM;
            const u16* nb = Qb + (size_t)(q0 + 48 + l15) * HDIM;
            nf0a = *(const short8*)(na + quad * 8);
            nf1a = *(const short8*)(na + 32 + quad * 8);
            nf0b = *(const short8*)(nb + quad * 8);
            nf1b = *(const short8*)(nb + 32 + quad * 8);
        }
        // A = K rows (m=k), B = Q rows (n=q): acc[r] = S[q_tile+l15][k0+quad*4+r]
        f32x4 aa = {0.f, 0.f, 0.f, 0.f}, ab = {0.f, 0.f, 0.f, 0.f};
        aa = __builtin_amdgcn_mfma_f32_16x16x32_bf16(kf0, cf0a, aa, 0, 0, 0);
        ab = __builtin_amdgcn_mfma_f32_16x16x32_bf16(kf0, cf0b, ab, 0, 0, 0);
        aa = __builtin_amdgcn_mfma_f32_16x16x32_bf16(kf1, cf1a, aa, 0, 0, 0);
        ab = __builtin_amdgcn_mfma_f32_16x16x32_bf16(kf1, cf1b, ab, 0, 0, 0);
        float e0 = __expf(aa[0]), e1 = __expf(aa[1]);
        float e2 = __expf(aa[2]), e3 = __expf(aa[3]);
        float g0 = __expf(ab[0]), g1 = __expf(ab[1]);
        float g2 = __expf(ab[2]), g3 = __expf(ab[3]);
        lacc[0] += e0 + g0; lacc[1] += e1 + g1;
        lacc[2] += e2 + g2; lacc[3] += e3 + g3;
        uint2 pa, pb;
        pa.x = (u32)f2bf(e0) | ((u32)f2bf(e1) << 16);
        pa.y = (u32)f2bf(e2) | ((u32)f2bf(e3) << 16);
        pb.x = (u32)f2bf(g0) | ((u32)f2bf(g1) << 16);
        pb.y = (u32)f2bf(g2) | ((u32)f2bf(g3) << 16);
        *(uint2*)(Wb + (size_t)(q0 + l15) * SEQ + k0 + quad * 4) = pa;
        *(uint2*)(Wb + (size_t)(q0 + 16 + l15) * SEQ + k0 + quad * 4) = pb;
        cf0a = nf0a; cf1a = nf1a; cf0b = nf0b; cf1b = nf1b;
    }
    // sum over l15 (q within tile): butterfly over lane bits 0..3
#pragma unroll
    for (int m = 1; m <= 8; m <<= 1) {
        lacc[0] += __shfl_xor(lacc[0], m, 64);
        lacc[1] += __shfl_xor(lacc[1], m, 64);
        lacc[2] += __shfl_xor(lacc[2], m, 64);
        lacc[3] += __shfl_xor(lacc[3], m, 64);
    }
    if (l15 == 0) {
        sl[w][quad * 4 + 0] = lacc[0];
        sl[w][quad * 4 + 1] = lacc[1];
        sl[w][quad * 4 + 2] = lacc[2];
        sl[w][quad * 4 + 3] = lacc[3];
    }
    __syncthreads();
    if (t < 16)
        invl[b * SEQ + k0 + t] =
            1.0f / ((sl[0][t] + sl[1][t]) + (sl[2][t] + sl[3][t]));
}

// ---------------------------------------------------------------------------
// K3: transpose + scale: hT[b][e][s] = bf16( h[b][s][e] * invl[b][s] ).
// 64x64 fp32 LDS tile; writes are full-wave 128B rows; LDS stride 65 ->
// bank = (c+er) % 32 (conflict-free). grid (S/64, E/64, B) x 256.
// ---------------------------------------------------------------------------
__global__ __launch_bounds__(256) void tscale_kernel(
    const float* __restrict__ h, const float* __restrict__ invl,
    u16* __restrict__ hT)
{
    __shared__ float tile[64][65];
    int b  = blockIdx.z;
    int s0 = blockIdx.x * 64, e0 = blockIdx.y * 64;
    int t = threadIdx.x, c = t & 63, r4 = t >> 6;
    const float* hb = h + (size_t)b * SEQ * EMBED;
    for (int r = r4; r < 64; r += 4)
        tile[r][c] = hb[(size_t)(s0 + r) * EMBED + e0 + c];
    __syncthreads();
    float il = invl[b * SEQ + s0 + c];   // thread's s-column
    u16* hTb = hT + (size_t)b * EMBED * SEQ;
    for (int er = r4; er < 64; er += 4)
        hTb[(size_t)(e0 + er) * SEQ + s0 + c] = f2bf(tile[c][er] * il);
}

// ---------------------------------------------------------------------------
// K4: out[b][q][e] = sum_k Wmat[b][q][k] * hT[b][e][k]
// Counted-vmcnt pipeline (T3/T4): BM=256 x BN=128 tile, BK=64, 512 thr
// (8 waves as 4Mx2N, each wave owns 64x64 = acc[4][4]).
// 3-slot LDS ring (A 32KB + B 16KB per slot = 144KB): tile kt+2 staged into
// the slot freed by the barrier opening iter kt -> depth-2 prefetch.
// Raw s_barrier + asm vmcnt(6) (6 = one in-flight tile x 6 loads/thread);
// never drains to 0 in the main loop. setprio(1) around the MFMA cluster.
// Swizzle: 128B rows = 8 chunks of 16B; phys chunk = logical ^ (row & 7),
// applied on the global SOURCE (gload_lds dest stays linear) and on ds_read.
// grid (2048/256, 1024/128, B) = (8,8,4) = 256 blocks = 1/CU; default
// block->XCD round-robin makes XCD == q-panel index (A-panel L2-resident).
// ---------------------------------------------------------------------------
__global__ __launch_bounds__(512, 2) void out_gemm_kernel(
    const u16* __restrict__ Wmat, const u16* __restrict__ hT, float* __restrict__ out)
{
    __shared__ u16 As[3][256 * 64];   // 96 KB
    __shared__ u16 Bs[3][128 * 64];   // 48 KB
    int b = blockIdx.z;
    int q0 = blockIdx.x * 256, e0 = blockIdx.y * 128;
    int t = threadIdx.x, lane = t & 63, w = t >> 6;
    int l15 = lane & 15, quad = lane >> 4;
    const u16* Wb  = Wmat + (size_t)b * SEQ * SEQ;
    const u16* hTb = hT + (size_t)b * EMBED * SEQ;
    int wm = w >> 1, wn = w & 1;
    int wq = wm * 64, we = wn * 64;

    f32x4 acc[4][4];
#pragma unroll
    for (int qi = 0; qi < 4; qi++)
#pragma unroll
        for (int ej = 0; ej < 4; ej++) acc[qi][ej] = (f32x4){0.f, 0.f, 0.f, 0.f};

    int st_rl = lane >> 3;            // row within 8-row group
    int st_pc = lane & 7;             // physical chunk at dest (= lane pattern)

    // 6 loads/thread per tile: A 4 (256 rows), B 2 (128 rows).
#define STAGE(si, k0)                                                          \
    {                                                                          \
        _Pragma("unroll")                                                      \
        for (int ld = 0; ld < 4; ld++) {                                       \
            int rowb = w * 32 + ld * 8;                                        \
            int row  = rowb + st_rl;                                           \
            int cg   = st_pc ^ (row & 7); /* logical source chunk */           \
            gload_lds16(Wb + (size_t)(q0 + row) * SEQ + (k0) + cg * 8,         \
                        &As[si][rowb * 64] + lane * 8);                        \
        }                                                                      \
        _Pragma("unroll")                                                      \
        for (int ld = 0; ld < 2; ld++) {                                       \
            int rowb = w * 16 + ld * 8;                                        \
            int row  = rowb + st_rl;                                           \
            int cg   = st_pc ^ (row & 7);                                      \
            gload_lds16(hTb + (size_t)(e0 + row) * SEQ + (k0) + cg * 8,        \
                        &Bs[si][rowb * 64] + lane * 8);                        \
        }                                                                      \
    }

    STAGE(0, 0)
    STAGE(1, 64)

    for (int kt = 0; kt < 32; ++kt) {
        int s = kt % 3;
        // Counted wait: tile kt's 6 loads done; tile kt+1's 6 may remain.
        if (kt == 31) { asm volatile("s_waitcnt vmcnt(0)" ::: "memory"); }
        else          { asm volatile("s_waitcnt vmcnt(6)" ::: "memory"); }
        __builtin_amdgcn_s_barrier();
        asm volatile("" ::: "memory");
        // Stage tile kt+2 into the slot freed by the barrier above
        // (slot (kt+2)%3 == (kt-1)%3, whose reads ended at that barrier).
        if (kt + 2 < 32) {
            int s2 = (kt + 2) % 3;
            STAGE(s2, (kt + 2) * 64)
        }
        asm volatile("" ::: "memory");

        const u16* Ab = &As[s][0];
        const u16* Bb = &Bs[s][0];
        short8 bfr[2][4], af[2][4];
#pragma unroll
        for (int kf = 0; kf < 2; kf++)
#pragma unroll
            for (int j = 0; j < 4; j++) {
                int rb  = we + j * 16 + l15;
                int pcb = (kf * 4 + quad) ^ (rb & 7);
                bfr[kf][j] = *(const short8*)(Bb + rb * 64 + pcb * 8);
            }
#pragma unroll
        for (int kf = 0; kf < 2; kf++)
#pragma unroll
            for (int i = 0; i < 4; i++) {
                int ra  = wq + i * 16 + l15;
                int pca = (kf * 4 + quad) ^ (ra & 7);
                af[kf][i] = *(const short8*)(Ab + ra * 64 + pca * 8);
            }
        __builtin_amdgcn_s_setprio(1);
#pragma unroll
        for (int kf = 0; kf < 2; kf++)
#pragma unroll
            for (int qi = 0; qi < 4; qi++)
#pragma unroll
                for (int ej = 0; ej < 4; ej++)
                    acc[qi][ej] = __builtin_amdgcn_mfma_f32_16x16x32_bf16(
                        af[kf][qi], bfr[kf][ej], acc[qi][ej], 0, 0, 0);
        __builtin_amdgcn_s_setprio(0);
    }
#undef STAGE

    float* outb = out + (size_t)b * SEQ * EMBED;
#pragma unroll
    for (int qi = 0; qi < 4; qi++)
#pragma unroll
        for (int ej = 0; ej < 4; ej++)
#pragma unroll
            for (int r = 0; r < 4; r++)
                outb[(size_t)(q0 + wq + qi * 16 + quad * 4 + r) * EMBED
                     + e0 + we + ej * 16 + l15] = acc[qi][ej][r];
}

// ---------------------------------------------------------------------------
extern "C" void kernel_launch(void* const* d_in, const int* in_sizes, int n_in,
                              void* d_out, int out_size, void* d_ws, size_t ws_size,
                              hipStream_t stream) {
    (void)in_sizes; (void)n_in; (void)out_size; (void)ws_size;
    const float* h  = (const float*)d_in[0];
    const float* Wq = (const float*)d_in[1];
    const float* bq = (const float*)d_in[2];
    const float* Wk = (const float*)d_in[3];
    const float* bk = (const float*)d_in[4];
    // d_in[5], d_in[6] (Wv, bv) are dead in the reference.
    float* out = (float*)d_out;

    char* ws = (char*)d_ws;
    u16*   Qbf  = (u16*)(ws);                                  // 1 MB
    u16*   Kbf  = (u16*)(ws + (1ull << 20));                   // 1 MB
    u16*   hT   = (u16*)(ws + (2ull << 20));                   // 16 MB
    float* invl = (float*)(ws + (18ull << 20));                // 32 KB
    u16*   WqT  = (u16*)(ws + (18ull << 20) + (128ull << 10)); // 128 KB
    u16*   WkT  = (u16*)(ws + (18ull << 20) + (256ull << 10)); // 128 KB
    u16*   Wmat = (u16*)(ws + (19ull << 20));                  // 32 MB (total ~51 MB)

    hipLaunchKernelGGL(wt_kernel, dim3(16, 2), dim3(256), 0, stream, Wq, Wk, WqT, WkT);
    hipLaunchKernelGGL(proj_kernel, dim3(512), dim3(256), 0, stream,
                       h, WqT, WkT, bq, bk, Qbf, Kbf);
    hipLaunchKernelGGL(sw_kernel, dim3(128, 4), dim3(256), 0, stream,
                       Qbf, Kbf, Wmat, invl);
    hipLaunchKernelGGL(tscale_kernel, dim3(32, 16, 4), dim3(256), 0, stream,
                       h, invl, hT);
    hipLaunchKernelGGL(out_gemm_kernel, dim3(8, 8, 4), dim3(512), 0, stream,
                       Wmat, hT, out);
}

// Round 2
// 178.208 us; speedup vs baseline: 1.0733x; 1.0315x over previous
//
#include <hip/hip_runtime.h>
#include <hip/hip_bf16.h>
#include <math.h>

#define EMBED 1024
#define HDIM  64
#define BATCH 4
#define SEQ   2048

typedef __attribute__((ext_vector_type(8))) short short8;
typedef __attribute__((ext_vector_type(4))) float f32x4;
typedef unsigned int u32;
typedef unsigned short u16;

static __device__ __forceinline__ u16 f2bf(float f) {
    union { float f; u32 u; } v; v.f = f;
    u32 r = v.u + 0x7fffu + ((v.u >> 16) & 1u);  // round-to-nearest-even
    return (u16)(r >> 16);
}

// async global->LDS, 16B per lane. LDS dest must equal uniform_base + lane*16.
static __device__ __forceinline__ void gload_lds16(const u16* g, u16* l) {
    __builtin_amdgcn_global_load_lds(
        (const __attribute__((address_space(1))) u32*)g,
        (__attribute__((address_space(3))) u32*)l, 16, 0, 0);
}

// ---------------------------------------------------------------------------
// K0: WqT[d][e] = bf16(Wq[e][d]), WkT likewise. grid (16,2) x 256.
// ---------------------------------------------------------------------------
__global__ __launch_bounds__(256) void wt_kernel(
    const float* __restrict__ Wq, const float* __restrict__ Wk,
    u16* __restrict__ WqT, u16* __restrict__ WkT)
{
    __shared__ float tile[64][65];
    const float* W = blockIdx.y ? Wk : Wq;
    u16* WT = blockIdx.y ? WkT : WqT;
    int e0 = blockIdx.x * 64;
    int t = threadIdx.x, c = t & 63, r4 = t >> 6;
    for (int r = r4; r < 64; r += 4)
        tile[r][c] = W[(size_t)(e0 + r) * HDIM + c];   // tile[e-e0][d]
    __syncthreads();
    for (int d = r4; d < 64; d += 4)
        WT[(size_t)d * EMBED + e0 + c] = f2bf(tile[c][d]);
}

// ---------------------------------------------------------------------------
// K1: proj only (transpose removed). Q = 0.125*(h*Wq+bq), K = h*Wk+bk.
// grid 512 (B * S/16), 256 thr, 16 s-rows/block, EC=128 per iter:
// 8 iters, 8 barriers, 8 MFMA + 4 ds_read_b128 per wave per iter.
// Double-buffered LDS; h and W-frags prefetched 1 iter ahead.
// ---------------------------------------------------------------------------
__global__ __launch_bounds__(256) void proj_kernel(
    const float* __restrict__ h, const u16* __restrict__ WqT, const u16* __restrict__ WkT,
    const float* __restrict__ bq, const float* __restrict__ bk,
    u16* __restrict__ Qbf, u16* __restrict__ Kbf)
{
    __shared__ u16 hs[2][16][136];   // 128 + 8 pad
    int b = blockIdx.x >> 7, s0 = (blockIdx.x & 127) * 16;
    int t = threadIdx.x, lane = t & 63, w = t >> 6;
    int l15 = lane & 15, quad = lane >> 4;
    int pj = w >> 1, nh = (w & 1) * 32;
    const float* hb = h + ((size_t)b * SEQ + s0) * EMBED;
    const u16* Wp = pj ? WkT : WqT;
    int r = t >> 4, c4 = (t & 15) * 4;   // staging: 16 rows x (16 f32x4 x 2 halves)

    f32x4 pre0 = *(const f32x4*)(hb + (size_t)r * EMBED + c4);
    f32x4 pre1 = *(const f32x4*)(hb + (size_t)r * EMBED + 64 + c4);
    f32x4 accA[2], accB[2];
    accA[0] = accA[1] = accB[0] = accB[1] = (f32x4){0.f, 0.f, 0.f, 0.f};

    const u16* Wrow0 = Wp + (size_t)(nh + l15) * EMBED;
    const u16* Wrow1 = Wp + (size_t)(nh + 16 + l15) * EMBED;

    short8 cw[8];
#pragma unroll
    for (int i = 0; i < 4; i++) {
        cw[i]     = *(const short8*)(Wrow0 + i * 32 + quad * 8);
        cw[4 + i] = *(const short8*)(Wrow1 + i * 32 + quad * 8);
    }

    for (int it = 0; it < 8; ++it) {
        int ec = it * 128, buf = it & 1;
        uint2 pk;
        pk.x = (u32)f2bf(pre0[0]) | ((u32)f2bf(pre0[1]) << 16);
        pk.y = (u32)f2bf(pre0[2]) | ((u32)f2bf(pre0[3]) << 16);
        *(uint2*)&hs[buf][r][c4] = pk;
        pk.x = (u32)f2bf(pre1[0]) | ((u32)f2bf(pre1[1]) << 16);
        pk.y = (u32)f2bf(pre1[2]) | ((u32)f2bf(pre1[3]) << 16);
        *(uint2*)&hs[buf][r][64 + c4] = pk;
        __syncthreads();

        if (it + 1 < 8) {
            pre0 = *(const f32x4*)(hb + (size_t)r * EMBED + ec + 128 + c4);
            pre1 = *(const f32x4*)(hb + (size_t)r * EMBED + ec + 192 + c4);
        }
        short8 nw[8];
#pragma unroll
        for (int i = 0; i < 8; i++) nw[i] = cw[i];
        if (it + 1 < 8) {
#pragma unroll
            for (int i = 0; i < 4; i++) {
                nw[i]     = *(const short8*)(Wrow0 + ec + 128 + i * 32 + quad * 8);
                nw[4 + i] = *(const short8*)(Wrow1 + ec + 128 + i * 32 + quad * 8);
            }
        }

        short8 a0 = *(const short8*)&hs[buf][l15][quad * 8];
        short8 a1 = *(const short8*)&hs[buf][l15][32 + quad * 8];
        short8 a2 = *(const short8*)&hs[buf][l15][64 + quad * 8];
        short8 a3 = *(const short8*)&hs[buf][l15][96 + quad * 8];
        // dependent accumulator reuses 4 apart
        accA[0] = __builtin_amdgcn_mfma_f32_16x16x32_bf16(a0, cw[0], accA[0], 0, 0, 0);
        accA[1] = __builtin_amdgcn_mfma_f32_16x16x32_bf16(a0, cw[4], accA[1], 0, 0, 0);
        accB[0] = __builtin_amdgcn_mfma_f32_16x16x32_bf16(a1, cw[1], accB[0], 0, 0, 0);
        accB[1] = __builtin_amdgcn_mfma_f32_16x16x32_bf16(a1, cw[5], accB[1], 0, 0, 0);
        accA[0] = __builtin_amdgcn_mfma_f32_16x16x32_bf16(a2, cw[2], accA[0], 0, 0, 0);
        accA[1] = __builtin_amdgcn_mfma_f32_16x16x32_bf16(a2, cw[6], accA[1], 0, 0, 0);
        accB[0] = __builtin_amdgcn_mfma_f32_16x16x32_bf16(a3, cw[3], accB[0], 0, 0, 0);
        accB[1] = __builtin_amdgcn_mfma_f32_16x16x32_bf16(a3, cw[7], accB[1], 0, 0, 0);
#pragma unroll
        for (int i = 0; i < 8; i++) cw[i] = nw[i];
    }

    const float* bias = pj ? bk : bq;
    float scale = pj ? 1.0f : 0.125f;
    u16* outp = pj ? Kbf : Qbf;
    float bv0 = bias[nh + l15], bv1 = bias[nh + 16 + l15];
#pragma unroll
    for (int rr = 0; rr < 4; rr++) {
        size_t row = (size_t)b * SEQ + s0 + quad * 4 + rr;
        outp[row * HDIM + nh + l15]      = f2bf((accA[0][rr] + accB[0][rr] + bv0) * scale);
        outp[row * HDIM + nh + 16 + l15] = f2bf((accA[1][rr] + accB[1][rr] + bv1) * scale);
    }
}

// ---------------------------------------------------------------------------
// K2: stats+weights SINGLE PASS. Block owns 16 k (k0) x all q; wave w owns
// q in [w*512,+512). K-frags loop-invariant. Per 32-q iter: 4 MFMA ->
// exp -> packed 8B stores of UNNORMALIZED exp(S) to Wmat + accumulate l.
// Ends writing invl[k] = 1/l[k]. grid (S/16, B) x 256.
// ---------------------------------------------------------------------------
__global__ __launch_bounds__(256) void sw_kernel(
    const u16* __restrict__ Qbf, const u16* __restrict__ Kbf,
    u16* __restrict__ Wmat, float* __restrict__ invl)
{
    __shared__ float sl[4][16];
    int b = blockIdx.y;
    int k0 = blockIdx.x * 16;
    int t = threadIdx.x, lane = t & 63, w = t >> 6;
    int l15 = lane & 15, quad = lane >> 4;
    const u16* Qb = Qbf + (size_t)b * SEQ * HDIM;
    const u16* Kb = Kbf + (size_t)b * SEQ * HDIM;
    u16* Wb = Wmat + (size_t)b * SEQ * SEQ;
    short8 kf0 = *(const short8*)(Kb + (size_t)(k0 + l15) * HDIM + quad * 8);
    short8 kf1 = *(const short8*)(Kb + (size_t)(k0 + l15) * HDIM + 32 + quad * 8);
    f32x4 lacc = {0.f, 0.f, 0.f, 0.f};
    int qs = w * 512;
    const u16* qpa = Qb + (size_t)(qs + l15) * HDIM;
    const u16* qpb = Qb + (size_t)(qs + 16 + l15) * HDIM;
    short8 cf0a = *(const short8*)(qpa + quad * 8);
    short8 cf1a = *(const short8*)(qpa + 32 + quad * 8);
    short8 cf0b = *(const short8*)(qpb + quad * 8);
    short8 cf1b = *(const short8*)(qpb + 32 + quad * 8);

    for (int q0 = qs; q0 < qs + 512; q0 += 32) {
        short8 nf0a = cf0a, nf1a = cf1a, nf0b = cf0b, nf1b = cf1b;
        if (q0 + 32 < qs + 512) {
            const u16* na = Qb + (size_t)(q0 + 32 + l15) * HDIM;
            const u16* nb = Qb + (size_t)(q0 + 48 + l15) * HDIM;
            nf0a = *(const short8*)(na + quad * 8);
            nf1a = *(const short8*)(na + 32 + quad * 8);
            nf0b = *(const short8*)(nb + quad * 8);
            nf1b = *(const short8*)(nb + 32 + quad * 8);
        }
        // A = K rows (m=k), B = Q rows (n=q): acc[r] = S[q_tile+l15][k0+quad*4+r]
        f32x4 aa = {0.f, 0.f, 0.f, 0.f}, ab = {0.f, 0.f, 0.f, 0.f};
        aa = __builtin_amdgcn_mfma_f32_16x16x32_bf16(kf0, cf0a, aa, 0, 0, 0);
        ab = __builtin_amdgcn_mfma_f32_16x16x32_bf16(kf0, cf0b, ab, 0, 0, 0);
        aa = __builtin_amdgcn_mfma_f32_16x16x32_bf16(kf1, cf1a, aa, 0, 0, 0);
        ab = __builtin_amdgcn_mfma_f32_16x16x32_bf16(kf1, cf1b, ab, 0, 0, 0);
        float e0 = __expf(aa[0]), e1 = __expf(aa[1]);
        float e2 = __expf(aa[2]), e3 = __expf(aa[3]);
        float g0 = __expf(ab[0]), g1 = __expf(ab[1]);
        float g2 = __expf(ab[2]), g3 = __expf(ab[3]);
        lacc[0] += e0 + g0; lacc[1] += e1 + g1;
        lacc[2] += e2 + g2; lacc[3] += e3 + g3;
        uint2 pa, pb;
        pa.x = (u32)f2bf(e0) | ((u32)f2bf(e1) << 16);
        pa.y = (u32)f2bf(e2) | ((u32)f2bf(e3) << 16);
        pb.x = (u32)f2bf(g0) | ((u32)f2bf(g1) << 16);
        pb.y = (u32)f2bf(g2) | ((u32)f2bf(g3) << 16);
        *(uint2*)(Wb + (size_t)(q0 + l15) * SEQ + k0 + quad * 4) = pa;
        *(uint2*)(Wb + (size_t)(q0 + 16 + l15) * SEQ + k0 + quad * 4) = pb;
        cf0a = nf0a; cf1a = nf1a; cf0b = nf0b; cf1b = nf1b;
    }
    // sum over l15 (q within tile): butterfly over lane bits 0..3
#pragma unroll
    for (int m = 1; m <= 8; m <<= 1) {
        lacc[0] += __shfl_xor(lacc[0], m, 64);
        lacc[1] += __shfl_xor(lacc[1], m, 64);
        lacc[2] += __shfl_xor(lacc[2], m, 64);
        lacc[3] += __shfl_xor(lacc[3], m, 64);
    }
    if (l15 == 0) {
        sl[w][quad * 4 + 0] = lacc[0];
        sl[w][quad * 4 + 1] = lacc[1];
        sl[w][quad * 4 + 2] = lacc[2];
        sl[w][quad * 4 + 3] = lacc[3];
    }
    __syncthreads();
    if (t < 16)
        invl[b * SEQ + k0 + t] =
            1.0f / ((sl[0][t] + sl[1][t]) + (sl[2][t] + sl[3][t]));
}

// ---------------------------------------------------------------------------
// K3: transpose + scale: hT[b][e][s] = bf16( h[b][s][e] * invl[b][s] ).
// 64x64 fp32 LDS tile; writes are full-wave 128B rows; LDS stride 65 ->
// bank = (c+er) % 32 (conflict-free). grid (S/64, E/64, B) x 256.
// ---------------------------------------------------------------------------
__global__ __launch_bounds__(256) void tscale_kernel(
    const float* __restrict__ h, const float* __restrict__ invl,
    u16* __restrict__ hT)
{
    __shared__ float tile[64][65];
    int b  = blockIdx.z;
    int s0 = blockIdx.x * 64, e0 = blockIdx.y * 64;
    int t = threadIdx.x, c = t & 63, r4 = t >> 6;
    const float* hb = h + (size_t)b * SEQ * EMBED;
    for (int r = r4; r < 64; r += 4)
        tile[r][c] = hb[(size_t)(s0 + r) * EMBED + e0 + c];
    __syncthreads();
    float il = invl[b * SEQ + s0 + c];   // thread's s-column
    u16* hTb = hT + (size_t)b * EMBED * SEQ;
    for (int er = r4; er < 64; er += 4)
        hTb[(size_t)(e0 + er) * SEQ + s0 + c] = f2bf(tile[c][er] * il);
}

// ---------------------------------------------------------------------------
// K4: out[b][q][e] = sum_k Wmat[b][q][k] * hT[b][e][k]
// Phase-split counted-vmcnt pipeline (T3+T4+T5): BM=256 x BN=128, BK=64,
// 512 thr (8 waves as 4Mx2N, wave owns 64x64 = acc[4][4]).
// 3-slot LDS ring (A 32KB + B 16KB per slot = 144KB), depth-2 prefetch.
// Per K-tile: 2 phases by k-half (kf). Each phase:
//   {8 ds_read_b128 || 3 gload_lds for tile kt+2} -> s_barrier ->
//   lgkmcnt(0)+sched_barrier(0) -> setprio(1) -> 16 MFMA -> setprio(0)
// The per-tile vmcnt(6) sits at END of phase 1, BEFORE the closing barrier:
// each wave waits on its own tile-(kt+1) loads, the barrier publishes them
// to all waves (cross-wave staging visibility). vmcnt never 0 until kt=30.
// Overlap mechanism: the pre-MFMA barrier syncs issue only; per-wave
// lgkmcnt(0) staggers actual MFMA start, so one wave's MFMA cluster covers
// the other wave's LDS reads on the same SIMD; setprio arbitrates.
// Swizzle: 128B rows = 8 chunks of 16B; phys chunk = logical ^ (row & 7),
// applied on the global SOURCE (gload_lds dest linear) and on ds_read.
// grid (8,8,4) = 256 blocks = 1/CU; default round-robin -> XCD == q-panel.
// ---------------------------------------------------------------------------
__global__ __launch_bounds__(512, 2) void out_gemm_kernel(
    const u16* __restrict__ Wmat, const u16* __restrict__ hT, float* __restrict__ out)
{
    __shared__ u16 As[3][256 * 64];   // 96 KB
    __shared__ u16 Bs[3][128 * 64];   // 48 KB
    int b = blockIdx.z;
    int q0 = blockIdx.x * 256, e0 = blockIdx.y * 128;
    int t = threadIdx.x, lane = t & 63, w = t >> 6;
    int l15 = lane & 15, quad = lane >> 4;
    const u16* Wb  = Wmat + (size_t)b * SEQ * SEQ;
    const u16* hTb = hT + (size_t)b * EMBED * SEQ;
    int wm = w >> 1, wn = w & 1;
    int wq = wm * 64, we = wn * 64;

    f32x4 acc[4][4];
#pragma unroll
    for (int qi = 0; qi < 4; qi++)
#pragma unroll
        for (int ej = 0; ej < 4; ej++) acc[qi][ej] = (f32x4){0.f, 0.f, 0.f, 0.f};

    int st_rl = lane >> 3;            // row within 8-row group
    int st_pc = lane & 7;             // physical chunk at dest (= lane pattern)

    // One A-row-group load (8 rows x 64 cols) / one B-row-group load.
#define STAGE_A(si, k0, ld)                                                    \
    {                                                                          \
        int rowb = w * 32 + (ld) * 8;                                          \
        int row  = rowb + st_rl;                                               \
        int cg   = st_pc ^ (row & 7); /* logical source chunk */               \
        gload_lds16(Wb + (size_t)(q0 + row) * SEQ + (k0) + cg * 8,             \
                    &As[si][rowb * 64] + lane * 8);                            \
    }
#define STAGE_B(si, k0, ld)                                                    \
    {                                                                          \
        int rowb = w * 16 + (ld) * 8;                                          \
        int row  = rowb + st_rl;                                               \
        int cg   = st_pc ^ (row & 7);                                          \
        gload_lds16(hTb + (size_t)(e0 + row) * SEQ + (k0) + cg * 8,            \
                    &Bs[si][rowb * 64] + lane * 8);                            \
    }

    // Phase fragment loads for k-half kf (8 x ds_read_b128).
#define LDFRAGS(kf)                                                            \
    {                                                                          \
        _Pragma("unroll")                                                      \
        for (int i = 0; i < 4; i++) {                                          \
            int ra  = wq + i * 16 + l15;                                       \
            int pca = ((kf) * 4 + quad) ^ (ra & 7);                            \
            af[i] = *(const short8*)(Ab + ra * 64 + pca * 8);                  \
        }                                                                      \
        _Pragma("unroll")                                                      \
        for (int j = 0; j < 4; j++) {                                          \
            int rb  = we + j * 16 + l15;                                       \
            int pcb = ((kf) * 4 + quad) ^ (rb & 7);                            \
            bfr[j] = *(const short8*)(Bb + rb * 64 + pcb * 8);                 \
        }                                                                      \
    }

#define MFMA16                                                                 \
    {                                                                          \
        _Pragma("unroll")                                                      \
        for (int qi = 0; qi < 4; qi++)                                         \
            _Pragma("unroll")                                                  \
            for (int ej = 0; ej < 4; ej++)                                     \
                acc[qi][ej] = __builtin_amdgcn_mfma_f32_16x16x32_bf16(         \
                    af[qi], bfr[ej], acc[qi][ej], 0, 0, 0);                    \
    }

    // Prologue: tile 0 (slot 0) fully, then tile 1 (slot 1) fully.
    STAGE_A(0, 0, 0) STAGE_A(0, 0, 1) STAGE_A(0, 0, 2) STAGE_A(0, 0, 3)
    STAGE_B(0, 0, 0) STAGE_B(0, 0, 1)
    STAGE_A(1, 64, 0) STAGE_A(1, 64, 1) STAGE_A(1, 64, 2) STAGE_A(1, 64, 3)
    STAGE_B(1, 64, 0) STAGE_B(1, 64, 1)
    asm volatile("s_waitcnt vmcnt(6)" ::: "memory");   // tile 0 (mine) done
    __builtin_amdgcn_s_barrier();                      // published to all

    for (int kt = 0; kt < 32; ++kt) {
        int s = kt % 3;
        const u16* Ab = &As[s][0];
        const u16* Bb = &Bs[s][0];
        int s2 = (kt + 2) % 3;
        int k2 = (kt + 2) * 64;
        bool st = (kt + 2) < 32;
        short8 af[4], bfr[4];

        // ---- phase 0: kf = 0 ----
        LDFRAGS(0)
        if (st) { STAGE_A(s2, k2, 0) STAGE_A(s2, k2, 1) STAGE_B(s2, k2, 0) }
        __builtin_amdgcn_s_barrier();
        asm volatile("s_waitcnt lgkmcnt(0)" ::: "memory");
        __builtin_amdgcn_sched_barrier(0);
        __builtin_amdgcn_s_setprio(1);
        MFMA16
        __builtin_amdgcn_s_setprio(0);
        __builtin_amdgcn_s_barrier();

        // ---- phase 1: kf = 1 ----
        LDFRAGS(1)
        if (st) { STAGE_A(s2, k2, 2) STAGE_A(s2, k2, 3) STAGE_B(s2, k2, 1) }
        __builtin_amdgcn_s_barrier();
        asm volatile("s_waitcnt lgkmcnt(0)" ::: "memory");
        __builtin_amdgcn_sched_barrier(0);
        __builtin_amdgcn_s_setprio(1);
        MFMA16
        __builtin_amdgcn_s_setprio(0);
        // Counted wait for tile kt+1 (own loads), published by the barrier.
        if (kt < 30)       { asm volatile("s_waitcnt vmcnt(6)" ::: "memory"); }
        else if (kt == 30) { asm volatile("s_waitcnt vmcnt(0)" ::: "memory"); }
        __builtin_amdgcn_s_barrier();
    }
#undef STAGE_A
#undef STAGE_B
#undef LDFRAGS
#undef MFMA16

    float* outb = out + (size_t)b * SEQ * EMBED;
#pragma unroll
    for (int qi = 0; qi < 4; qi++)
#pragma unroll
        for (int ej = 0; ej < 4; ej++)
#pragma unroll
            for (int r = 0; r < 4; r++)
                outb[(size_t)(q0 + wq + qi * 16 + quad * 4 + r) * EMBED
                     + e0 + we + ej * 16 + l15] = acc[qi][ej][r];
}

// ---------------------------------------------------------------------------
extern "C" void kernel_launch(void* const* d_in, const int* in_sizes, int n_in,
                              void* d_out, int out_size, void* d_ws, size_t ws_size,
                              hipStream_t stream) {
    (void)in_sizes; (void)n_in; (void)out_size; (void)ws_size;
    const float* h  = (const float*)d_in[0];
    const float* Wq = (const float*)d_in[1];
    const float* bq = (const float*)d_in[2];
    const float* Wk = (const float*)d_in[3];
    const float* bk = (const float*)d_in[4];
    // d_in[5], d_in[6] (Wv, bv) are dead in the reference.
    float* out = (float*)d_out;

    char* ws = (char*)d_ws;
    u16*   Qbf  = (u16*)(ws);                                  // 1 MB
    u16*   Kbf  = (u16*)(ws + (1ull << 20));                   // 1 MB
    u16*   hT   = (u16*)(ws + (2ull << 20));                   // 16 MB
    float* invl = (float*)(ws + (18ull << 20));                // 32 KB
    u16*   WqT  = (u16*)(ws + (18ull << 20) + (128ull << 10)); // 128 KB
    u16*   WkT  = (u16*)(ws + (18ull << 20) + (256ull << 10)); // 128 KB
    u16*   Wmat = (u16*)(ws + (19ull << 20));                  // 32 MB (total ~51 MB)

    hipLaunchKernelGGL(wt_kernel, dim3(16, 2), dim3(256), 0, stream, Wq, Wk, WqT, WkT);
    hipLaunchKernelGGL(proj_kernel, dim3(512), dim3(256), 0, stream,
                       h, WqT, WkT, bq, bk, Qbf, Kbf);
    hipLaunchKernelGGL(sw_kernel, dim3(128, 4), dim3(256), 0, stream,
                       Qbf, Kbf, Wmat, invl);
    hipLaunchKernelGGL(tscale_kernel, dim3(32, 16, 4), dim3(256), 0, stream,
                       h, invl, hT);
    hipLaunchKernelGGL(out_gemm_kernel, dim3(8, 8, 4), dim3(512), 0, stream,
                       Wmat, hT, out);
}

// Round 3
// 174.010 us; speedup vs baseline: 1.0992x; 1.0241x over previous
//
#include <hip/hip_runtime.h>
#include <hip/hip_bf16.h>
#include <math.h>

#define EMBED 1024
#define HDIM  64
#define BATCH 4
#define SEQ   2048

typedef __attribute__((ext_vector_type(8))) short short8;
typedef __attribute__((ext_vector_type(4))) float f32x4;
typedef unsigned int u32;
typedef unsigned short u16;

static __device__ __forceinline__ u16 f2bf(float f) {
    union { float f; u32 u; } v; v.f = f;
    u32 r = v.u + 0x7fffu + ((v.u >> 16) & 1u);  // round-to-nearest-even
    return (u16)(r >> 16);
}

// async global->LDS, 16B per lane. LDS dest must equal uniform_base + lane*16.
static __device__ __forceinline__ void gload_lds16(const u16* g, u16* l) {
    __builtin_amdgcn_global_load_lds(
        (const __attribute__((address_space(1))) u32*)g,
        (__attribute__((address_space(3))) u32*)l, 16, 0, 0);
}

// ---------------------------------------------------------------------------
// K0: WqT[d][e] = bf16(Wq[e][d]), WkT likewise. grid (16,2) x 256.
// ---------------------------------------------------------------------------
__global__ __launch_bounds__(256) void wt_kernel(
    const float* __restrict__ Wq, const float* __restrict__ Wk,
    u16* __restrict__ WqT, u16* __restrict__ WkT)
{
    __shared__ float tile[64][65];
    const float* W = blockIdx.y ? Wk : Wq;
    u16* WT = blockIdx.y ? WkT : WqT;
    int e0 = blockIdx.x * 64;
    int t = threadIdx.x, c = t & 63, r4 = t >> 6;
    for (int r = r4; r < 64; r += 4)
        tile[r][c] = W[(size_t)(e0 + r) * HDIM + c];   // tile[e-e0][d]
    __syncthreads();
    for (int d = r4; d < 64; d += 4)
        WT[(size_t)d * EMBED + e0 + c] = f2bf(tile[c][d]);
}

// ---------------------------------------------------------------------------
// K1: proj only (transpose removed). Q = 0.125*(h*Wq+bq), K = h*Wk+bk.
// grid 512 (B * S/16), 256 thr, 16 s-rows/block, EC=128 per iter:
// 8 iters, 8 barriers, 8 MFMA + 4 ds_read_b128 per wave per iter.
// Double-buffered LDS; h prefetched DEPTH-2 (hides ~900cyc HBM latency),
// W-frags prefetched 1 iter ahead (L2-resident).
// ---------------------------------------------------------------------------
__global__ __launch_bounds__(256) void proj_kernel(
    const float* __restrict__ h, const u16* __restrict__ WqT, const u16* __restrict__ WkT,
    const float* __restrict__ bq, const float* __restrict__ bk,
    u16* __restrict__ Qbf, u16* __restrict__ Kbf)
{
    __shared__ u16 hs[2][16][136];   // 128 + 8 pad
    int b = blockIdx.x >> 7, s0 = (blockIdx.x & 127) * 16;
    int t = threadIdx.x, lane = t & 63, w = t >> 6;
    int l15 = lane & 15, quad = lane >> 4;
    int pj = w >> 1, nh = (w & 1) * 32;
    const float* hb = h + ((size_t)b * SEQ + s0) * EMBED;
    const u16* Wp = pj ? WkT : WqT;
    int r = t >> 4, c4 = (t & 15) * 4;   // staging: 16 rows x (16 f32x4 x 2 halves)

    f32x4 preA0 = *(const f32x4*)(hb + (size_t)r * EMBED + c4);
    f32x4 preA1 = *(const f32x4*)(hb + (size_t)r * EMBED + 64 + c4);
    f32x4 preB0 = *(const f32x4*)(hb + (size_t)r * EMBED + 128 + c4);
    f32x4 preB1 = *(const f32x4*)(hb + (size_t)r * EMBED + 192 + c4);
    f32x4 accA[2], accB[2];
    accA[0] = accA[1] = accB[0] = accB[1] = (f32x4){0.f, 0.f, 0.f, 0.f};

    const u16* Wrow0 = Wp + (size_t)(nh + l15) * EMBED;
    const u16* Wrow1 = Wp + (size_t)(nh + 16 + l15) * EMBED;

    short8 cw[8];
#pragma unroll
    for (int i = 0; i < 4; i++) {
        cw[i]     = *(const short8*)(Wrow0 + i * 32 + quad * 8);
        cw[4 + i] = *(const short8*)(Wrow1 + i * 32 + quad * 8);
    }

    for (int it = 0; it < 8; ++it) {
        int ec = it * 128, buf = it & 1;
        uint2 pk;
        pk.x = (u32)f2bf(preA0[0]) | ((u32)f2bf(preA0[1]) << 16);
        pk.y = (u32)f2bf(preA0[2]) | ((u32)f2bf(preA0[3]) << 16);
        *(uint2*)&hs[buf][r][c4] = pk;
        pk.x = (u32)f2bf(preA1[0]) | ((u32)f2bf(preA1[1]) << 16);
        pk.y = (u32)f2bf(preA1[2]) | ((u32)f2bf(preA1[3]) << 16);
        *(uint2*)&hs[buf][r][64 + c4] = pk;
        __syncthreads();

        preA0 = preB0; preA1 = preB1;
        if (it + 2 < 8) {
            preB0 = *(const f32x4*)(hb + (size_t)r * EMBED + ec + 256 + c4);
            preB1 = *(const f32x4*)(hb + (size_t)r * EMBED + ec + 320 + c4);
        }
        short8 nw[8];
#pragma unroll
        for (int i = 0; i < 8; i++) nw[i] = cw[i];
        if (it + 1 < 8) {
#pragma unroll
            for (int i = 0; i < 4; i++) {
                nw[i]     = *(const short8*)(Wrow0 + ec + 128 + i * 32 + quad * 8);
                nw[4 + i] = *(const short8*)(Wrow1 + ec + 128 + i * 32 + quad * 8);
            }
        }

        short8 a0 = *(const short8*)&hs[buf][l15][quad * 8];
        short8 a1 = *(const short8*)&hs[buf][l15][32 + quad * 8];
        short8 a2 = *(const short8*)&hs[buf][l15][64 + quad * 8];
        short8 a3 = *(const short8*)&hs[buf][l15][96 + quad * 8];
        // dependent accumulator reuses 4 apart
        accA[0] = __builtin_amdgcn_mfma_f32_16x16x32_bf16(a0, cw[0], accA[0], 0, 0, 0);
        accA[1] = __builtin_amdgcn_mfma_f32_16x16x32_bf16(a0, cw[4], accA[1], 0, 0, 0);
        accB[0] = __builtin_amdgcn_mfma_f32_16x16x32_bf16(a1, cw[1], accB[0], 0, 0, 0);
        accB[1] = __builtin_amdgcn_mfma_f32_16x16x32_bf16(a1, cw[5], accB[1], 0, 0, 0);
        accA[0] = __builtin_amdgcn_mfma_f32_16x16x32_bf16(a2, cw[2], accA[0], 0, 0, 0);
        accA[1] = __builtin_amdgcn_mfma_f32_16x16x32_bf16(a2, cw[6], accA[1], 0, 0, 0);
        accB[0] = __builtin_amdgcn_mfma_f32_16x16x32_bf16(a3, cw[3], accB[0], 0, 0, 0);
        accB[1] = __builtin_amdgcn_mfma_f32_16x16x32_bf16(a3, cw[7], accB[1], 0, 0, 0);
#pragma unroll
        for (int i = 0; i < 8; i++) cw[i] = nw[i];
    }

    const float* bias = pj ? bk : bq;
    float scale = pj ? 1.0f : 0.125f;
    u16* outp = pj ? Kbf : Qbf;
    float bv0 = bias[nh + l15], bv1 = bias[nh + 16 + l15];
#pragma unroll
    for (int rr = 0; rr < 4; rr++) {
        size_t row = (size_t)b * SEQ + s0 + quad * 4 + rr;
        outp[row * HDIM + nh + l15]      = f2bf((accA[0][rr] + accB[0][rr] + bv0) * scale);
        outp[row * HDIM + nh + 16 + l15] = f2bf((accA[1][rr] + accB[1][rr] + bv1) * scale);
    }
}

// ---------------------------------------------------------------------------
// K2: stats+weights SINGLE PASS. Block owns 16 k (k0) x all q; wave w owns
// q in [w*512,+512). K-frags loop-invariant. Per 32-q iter: 4 MFMA ->
// exp -> packed 8B stores of UNNORMALIZED exp(S) to Wmat + accumulate l.
// Ends writing invl[k] = 1/l[k]. grid (S/16, B) x 256.
// ---------------------------------------------------------------------------
__global__ __launch_bounds__(256) void sw_kernel(
    const u16* __restrict__ Qbf, const u16* __restrict__ Kbf,
    u16* __restrict__ Wmat, float* __restrict__ invl)
{
    __shared__ float sl[4][16];
    int b = blockIdx.y;
    int k0 = blockIdx.x * 16;
    int t = threadIdx.x, lane = t & 63, w = t >> 6;
    int l15 = lane & 15, quad = lane >> 4;
    const u16* Qb = Qbf + (size_t)b * SEQ * HDIM;
    const u16* Kb = Kbf + (size_t)b * SEQ * HDIM;
    u16* Wb = Wmat + (size_t)b * SEQ * SEQ;
    short8 kf0 = *(const short8*)(Kb + (size_t)(k0 + l15) * HDIM + quad * 8);
    short8 kf1 = *(const short8*)(Kb + (size_t)(k0 + l15) * HDIM + 32 + quad * 8);
    f32x4 lacc = {0.f, 0.f, 0.f, 0.f};
    int qs = w * 512;
    const u16* qpa = Qb + (size_t)(qs + l15) * HDIM;
    const u16* qpb = Qb + (size_t)(qs + 16 + l15) * HDIM;
    short8 cf0a = *(const short8*)(qpa + quad * 8);
    short8 cf1a = *(const short8*)(qpa + 32 + quad * 8);
    short8 cf0b = *(const short8*)(qpb + quad * 8);
    short8 cf1b = *(const short8*)(qpb + 32 + quad * 8);

    for (int q0 = qs; q0 < qs + 512; q0 += 32) {
        short8 nf0a = cf0a, nf1a = cf1a, nf0b = cf0b, nf1b = cf1b;
        if (q0 + 32 < qs + 512) {
            const u16* na = Qb + (size_t)(q0 + 32 + l15) * HDIM;
            const u16* nb = Qb + (size_t)(q0 + 48 + l15) * HDIM;
            nf0a = *(const short8*)(na + quad * 8);
            nf1a = *(const short8*)(na + 32 + quad * 8);
            nf0b = *(const short8*)(nb + quad * 8);
            nf1b = *(const short8*)(nb + 32 + quad * 8);
        }
        // A = K rows (m=k), B = Q rows (n=q): acc[r] = S[q_tile+l15][k0+quad*4+r]
        f32x4 aa = {0.f, 0.f, 0.f, 0.f}, ab = {0.f, 0.f, 0.f, 0.f};
        aa = __builtin_amdgcn_mfma_f32_16x16x32_bf16(kf0, cf0a, aa, 0, 0, 0);
        ab = __builtin_amdgcn_mfma_f32_16x16x32_bf16(kf0, cf0b, ab, 0, 0, 0);
        aa = __builtin_amdgcn_mfma_f32_16x16x32_bf16(kf1, cf1a, aa, 0, 0, 0);
        ab = __builtin_amdgcn_mfma_f32_16x16x32_bf16(kf1, cf1b, ab, 0, 0, 0);
        float e0 = __expf(aa[0]), e1 = __expf(aa[1]);
        float e2 = __expf(aa[2]), e3 = __expf(aa[3]);
        float g0 = __expf(ab[0]), g1 = __expf(ab[1]);
        float g2 = __expf(ab[2]), g3 = __expf(ab[3]);
        lacc[0] += e0 + g0; lacc[1] += e1 + g1;
        lacc[2] += e2 + g2; lacc[3] += e3 + g3;
        uint2 pa, pb;
        pa.x = (u32)f2bf(e0) | ((u32)f2bf(e1) << 16);
        pa.y = (u32)f2bf(e2) | ((u32)f2bf(e3) << 16);
        pb.x = (u32)f2bf(g0) | ((u32)f2bf(g1) << 16);
        pb.y = (u32)f2bf(g2) | ((u32)f2bf(g3) << 16);
        *(uint2*)(Wb + (size_t)(q0 + l15) * SEQ + k0 + quad * 4) = pa;
        *(uint2*)(Wb + (size_t)(q0 + 16 + l15) * SEQ + k0 + quad * 4) = pb;
        cf0a = nf0a; cf1a = nf1a; cf0b = nf0b; cf1b = nf1b;
    }
    // sum over l15 (q within tile): butterfly over lane bits 0..3
#pragma unroll
    for (int m = 1; m <= 8; m <<= 1) {
        lacc[0] += __shfl_xor(lacc[0], m, 64);
        lacc[1] += __shfl_xor(lacc[1], m, 64);
        lacc[2] += __shfl_xor(lacc[2], m, 64);
        lacc[3] += __shfl_xor(lacc[3], m, 64);
    }
    if (l15 == 0) {
        sl[w][quad * 4 + 0] = lacc[0];
        sl[w][quad * 4 + 1] = lacc[1];
        sl[w][quad * 4 + 2] = lacc[2];
        sl[w][quad * 4 + 3] = lacc[3];
    }
    __syncthreads();
    if (t < 16)
        invl[b * SEQ + k0 + t] =
            1.0f / ((sl[0][t] + sl[1][t]) + (sl[2][t] + sl[3][t]));
}

// ---------------------------------------------------------------------------
// K3: transpose + scale: hT[b][e][s] = bf16( h[b][s][e] * invl[b][s] ).
// 64x64 fp32 LDS tile, f32x4 global loads (coalesced), uint2 packed stores
// (4x fewer store instrs). LDS stride 65 keeps both phases ~conflict-free
// (2-way max = free). grid (S/64, E/64, B) x 256.
// ---------------------------------------------------------------------------
__global__ __launch_bounds__(256) void tscale_kernel(
    const float* __restrict__ h, const float* __restrict__ invl,
    u16* __restrict__ hT)
{
    __shared__ float tile[64][65];
    int b  = blockIdx.z;
    int s0 = blockIdx.x * 64, e0 = blockIdx.y * 64;
    int t = threadIdx.x;
    int r16 = t >> 4, c4 = (t & 15) * 4;
    const float* hb = h + (size_t)b * SEQ * EMBED;
#pragma unroll
    for (int rr = r16; rr < 64; rr += 16) {
        f32x4 v = *(const f32x4*)(hb + (size_t)(s0 + rr) * EMBED + e0 + c4);
        *(f32x4*)&tile[rr][c4] = v;
    }
    __syncthreads();
    f32x4 il4 = *(const f32x4*)(invl + b * SEQ + s0 + c4);   // 4 s-columns
    u16* hTb = hT + (size_t)b * EMBED * SEQ;
#pragma unroll
    for (int er = r16; er < 64; er += 16) {
        u16 p0 = f2bf(tile[c4 + 0][er] * il4[0]);
        u16 p1 = f2bf(tile[c4 + 1][er] * il4[1]);
        u16 p2 = f2bf(tile[c4 + 2][er] * il4[2]);
        u16 p3 = f2bf(tile[c4 + 3][er] * il4[3]);
        uint2 pk;
        pk.x = (u32)p0 | ((u32)p1 << 16);
        pk.y = (u32)p2 | ((u32)p3 << 16);
        *(uint2*)(hTb + (size_t)(e0 + er) * SEQ + s0 + c4) = pk;
    }
}

// ---------------------------------------------------------------------------
// K4: out[b][q][e] = sum_k Wmat[b][q][k] * hT[b][e][k]
// V3: k-half-split wave groups. BM=256 x BN=128, BK=64, 512 thr = 8 waves
// = 2 kf-groups x 2M x 2N; EACH wave has tile 128x64 (acc[8][4]) over its
// 32-wide k-half -> LDS frag reads drop to 12 KB/wave/K-tile (A8+B4, B
// reused across m-half phases); per-CU LDS reads 96 KB/tile (was 128).
// Ring/staging unchanged: 3-slot 144KB, depth-2 prefetch, vmcnt(6) counted.
// Per K-tile 2 phases (m-half): {ds_reads || 3 gloads} -> barrier ->
// lgkmcnt(0)+sched_barrier -> setprio(1) -> 16 MFMA -> setprio(0) -> barrier.
// Epilogue: kf=1 waves write acc to retired ring LDS (lane-contiguous b128,
// conflict-free); paired kf=0 waves add + store.
// Swizzle: phys chunk = logical ^ (row&7) on global source + ds_read side.
// grid (8,8,4) = 256 blocks = 1/CU; A-panels get XCD L2 locality free.
// ---------------------------------------------------------------------------
__global__ __launch_bounds__(512, 2) void out_gemm_kernel(
    const u16* __restrict__ Wmat, const u16* __restrict__ hT, float* __restrict__ out)
{
    __shared__ __align__(16) char smem[3 * 49152];   // 3 x (A 32KB + B 16KB)
#define ASLOT(si) ((u16*)(smem + (size_t)(si) * 49152))
#define BSLOT(si) ((u16*)(smem + (size_t)(si) * 49152 + 32768))
    int b = blockIdx.z;
    int q0 = blockIdx.x * 256, e0 = blockIdx.y * 128;
    int t = threadIdx.x, lane = t & 63, w = t >> 6;
    int l15 = lane & 15, quad = lane >> 4;
    const u16* Wb  = Wmat + (size_t)b * SEQ * SEQ;
    const u16* hTb = hT + (size_t)b * EMBED * SEQ;
    int kf = w >> 2;                 // k-half group (0: k 0..31, 1: k 32..63)
    int wm = (w >> 1) & 1, wn = w & 1;
    int wq = wm * 128, we = wn * 64; // wave tile origin (128 x 64)

    f32x4 acc[8][4];
#pragma unroll
    for (int i = 0; i < 8; i++)
#pragma unroll
        for (int j = 0; j < 4; j++) acc[i][j] = (f32x4){0.f, 0.f, 0.f, 0.f};

    int st_rl = lane >> 3;            // row within 8-row group
    int st_pc = lane & 7;             // physical chunk at dest (= lane pattern)

    // 6 loads/thread per tile: A 4 (256 rows), B 2 (128 rows).
#define STAGE_A(si, k0, ld)                                                    \
    {                                                                          \
        int rowb = w * 32 + (ld) * 8;                                          \
        int row  = rowb + st_rl;                                               \
        int cg   = st_pc ^ (row & 7); /* logical source chunk */               \
        gload_lds16(Wb + (size_t)(q0 + row) * SEQ + (k0) + cg * 8,             \
                    ASLOT(si) + rowb * 64 + lane * 8);                         \
    }
#define STAGE_B(si, k0, ld)                                                    \
    {                                                                          \
        int rowb = w * 16 + (ld) * 8;                                          \
        int row  = rowb + st_rl;                                               \
        int cg   = st_pc ^ (row & 7);                                          \
        gload_lds16(hTb + (size_t)(e0 + row) * SEQ + (k0) + cg * 8,            \
                    BSLOT(si) + rowb * 64 + lane * 8);                         \
    }

    // A-frags i0..i0+3 for this wave's kf-half.
#define LDFRAGS_A(i0)                                                          \
    {                                                                          \
        _Pragma("unroll")                                                      \
        for (int ii = 0; ii < 4; ii++) {                                       \
            int ra  = wq + ((i0) + ii) * 16 + l15;                             \
            int pca = (kf * 4 + quad) ^ (ra & 7);                              \
            af[ii] = *(const short8*)(Ab + ra * 64 + pca * 8);                 \
        }                                                                      \
    }
#define LDFRAGS_B                                                              \
    {                                                                          \
        _Pragma("unroll")                                                      \
        for (int j = 0; j < 4; j++) {                                          \
            int rb  = we + j * 16 + l15;                                       \
            int pcb = (kf * 4 + quad) ^ (rb & 7);                              \
            bfr[j] = *(const short8*)(Bb + rb * 64 + pcb * 8);                 \
        }                                                                      \
    }

#define MFMA16(i0)                                                             \
    {                                                                          \
        _Pragma("unroll")                                                      \
        for (int ii = 0; ii < 4; ii++)                                         \
            _Pragma("unroll")                                                  \
            for (int j = 0; j < 4; j++)                                        \
                acc[(i0) + ii][j] = __builtin_amdgcn_mfma_f32_16x16x32_bf16(   \
                    af[ii], bfr[j], acc[(i0) + ii][j], 0, 0, 0);               \
    }

    // Prologue: tile 0 (slot 0) fully, then tile 1 (slot 1) fully.
    STAGE_A(0, 0, 0) STAGE_A(0, 0, 1) STAGE_A(0, 0, 2) STAGE_A(0, 0, 3)
    STAGE_B(0, 0, 0) STAGE_B(0, 0, 1)
    STAGE_A(1, 64, 0) STAGE_A(1, 64, 1) STAGE_A(1, 64, 2) STAGE_A(1, 64, 3)
    STAGE_B(1, 64, 0) STAGE_B(1, 64, 1)
    asm volatile("s_waitcnt vmcnt(6)" ::: "memory");   // tile 0 (mine) done
    __builtin_amdgcn_s_barrier();                      // published to all

    for (int kt = 0; kt < 32; ++kt) {
        int s = kt % 3;
        const u16* Ab = ASLOT(s);
        const u16* Bb = BSLOT(s);
        int s2 = (kt + 2) % 3;
        int k2 = (kt + 2) * 64 + kf * 0;   // kf only affects ds_read side
        bool st = (kt + 2) < 32;
        short8 af[4], bfr[4];

        // ---- phase 0: m-half 0 (+ B frags, reused in phase 1) ----
        LDFRAGS_A(0)
        LDFRAGS_B
        if (st) { STAGE_A(s2, k2, 0) STAGE_A(s2, k2, 1) STAGE_B(s2, k2, 0) }
        __builtin_amdgcn_s_barrier();
        asm volatile("s_waitcnt lgkmcnt(0)" ::: "memory");
        __builtin_amdgcn_sched_barrier(0);
        __builtin_amdgcn_s_setprio(1);
        MFMA16(0)
        __builtin_amdgcn_s_setprio(0);
        __builtin_amdgcn_s_barrier();

        // ---- phase 1: m-half 1 ----
        LDFRAGS_A(4)
        if (st) { STAGE_A(s2, k2, 2) STAGE_A(s2, k2, 3) STAGE_B(s2, k2, 1) }
        __builtin_amdgcn_s_barrier();
        asm volatile("s_waitcnt lgkmcnt(0)" ::: "memory");
        __builtin_amdgcn_sched_barrier(0);
        __builtin_amdgcn_s_setprio(1);
        MFMA16(4)
        __builtin_amdgcn_s_setprio(0);
        // Counted wait for tile kt+1 (own loads), published by the barrier.
        if (kt < 30)       { asm volatile("s_waitcnt vmcnt(6)" ::: "memory"); }
        else if (kt == 30) { asm volatile("s_waitcnt vmcnt(0)" ::: "memory"); }
        __builtin_amdgcn_s_barrier();
    }
#undef STAGE_A
#undef STAGE_B
#undef LDFRAGS_A
#undef LDFRAGS_B
#undef MFMA16

    // Epilogue: combine kf=1 partials into kf=0 waves via retired ring LDS.
    // Region per wave-pair (w&3): 32KB = 32 frags x 64 lanes x 16B.
    float* red = (float*)smem;
    if (w >= 4) {
        float* reg = red + (size_t)(w & 3) * 8192;
#pragma unroll
        for (int i = 0; i < 8; i++)
#pragma unroll
            for (int j = 0; j < 4; j++)
                *(f32x4*)(reg + ((i * 4 + j) * 64 + lane) * 4) = acc[i][j];
    }
    __syncthreads();
    if (w < 4) {
        float* reg = red + (size_t)w * 8192;
        float* outb = out + (size_t)b * SEQ * EMBED;
#pragma unroll
        for (int i = 0; i < 8; i++)
#pragma unroll
            for (int j = 0; j < 4; j++) {
                f32x4 o = *(const f32x4*)(reg + ((i * 4 + j) * 64 + lane) * 4);
                o += acc[i][j];
#pragma unroll
                for (int r = 0; r < 4; r++)
                    outb[(size_t)(q0 + wq + i * 16 + quad * 4 + r) * EMBED
                         + e0 + we + j * 16 + l15] = o[r];
            }
    }
#undef ASLOT
#undef BSLOT
}

// ---------------------------------------------------------------------------
extern "C" void kernel_launch(void* const* d_in, const int* in_sizes, int n_in,
                              void* d_out, int out_size, void* d_ws, size_t ws_size,
                              hipStream_t stream) {
    (void)in_sizes; (void)n_in; (void)out_size; (void)ws_size;
    const float* h  = (const float*)d_in[0];
    const float* Wq = (const float*)d_in[1];
    const float* bq = (const float*)d_in[2];
    const float* Wk = (const float*)d_in[3];
    const float* bk = (const float*)d_in[4];
    // d_in[5], d_in[6] (Wv, bv) are dead in the reference.
    float* out = (float*)d_out;

    char* ws = (char*)d_ws;
    u16*   Qbf  = (u16*)(ws);                                  // 1 MB
    u16*   Kbf  = (u16*)(ws + (1ull << 20));                   // 1 MB
    u16*   hT   = (u16*)(ws + (2ull << 20));                   // 16 MB
    float* invl = (float*)(ws + (18ull << 20));                // 32 KB
    u16*   WqT  = (u16*)(ws + (18ull << 20) + (128ull << 10)); // 128 KB
    u16*   WkT  = (u16*)(ws + (18ull << 20) + (256ull << 10)); // 128 KB
    u16*   Wmat = (u16*)(ws + (19ull << 20));                  // 32 MB (total ~51 MB)

    hipLaunchKernelGGL(wt_kernel, dim3(16, 2), dim3(256), 0, stream, Wq, Wk, WqT, WkT);
    hipLaunchKernelGGL(proj_kernel, dim3(512), dim3(256), 0, stream,
                       h, WqT, WkT, bq, bk, Qbf, Kbf);
    hipLaunchKernelGGL(sw_kernel, dim3(128, 4), dim3(256), 0, stream,
                       Qbf, Kbf, Wmat, invl);
    hipLaunchKernelGGL(tscale_kernel, dim3(32, 16, 4), dim3(256), 0, stream,
                       h, invl, hT);
    hipLaunchKernelGGL(out_gemm_kernel, dim3(8, 8, 4), dim3(512), 0, stream,
                       Wmat, hT, out);
}

// Round 4
// 173.879 us; speedup vs baseline: 1.1000x; 1.0008x over previous
//
#include <hip/hip_runtime.h>
#include <hip/hip_bf16.h>
#include <math.h>

#define EMBED 1024
#define HDIM  64
#define BATCH 4
#define SEQ   2048

typedef __attribute__((ext_vector_type(8))) short short8;
typedef __attribute__((ext_vector_type(4))) float f32x4;
typedef unsigned int u32;
typedef unsigned short u16;

static __device__ __forceinline__ u16 f2bf(float f) {
    union { float f; u32 u; } v; v.f = f;
    u32 r = v.u + 0x7fffu + ((v.u >> 16) & 1u);  // round-to-nearest-even
    return (u16)(r >> 16);
}

// async global->LDS, 16B per lane. LDS dest must equal uniform_base + lane*16.
static __device__ __forceinline__ void gload_lds16(const u16* g, u16* l) {
    __builtin_amdgcn_global_load_lds(
        (const __attribute__((address_space(1))) u32*)g,
        (__attribute__((address_space(3))) u32*)l, 16, 0, 0);
}

// ---------------------------------------------------------------------------
// K0: WqT[d][e] = bf16(Wq[e][d]), WkT likewise. grid (16,2) x 256.
// ---------------------------------------------------------------------------
__global__ __launch_bounds__(256) void wt_kernel(
    const float* __restrict__ Wq, const float* __restrict__ Wk,
    u16* __restrict__ WqT, u16* __restrict__ WkT)
{
    __shared__ float tile[64][65];
    const float* W = blockIdx.y ? Wk : Wq;
    u16* WT = blockIdx.y ? WkT : WqT;
    int e0 = blockIdx.x * 64;
    int t = threadIdx.x, c = t & 63, r4 = t >> 6;
    for (int r = r4; r < 64; r += 4)
        tile[r][c] = W[(size_t)(e0 + r) * HDIM + c];   // tile[e-e0][d]
    __syncthreads();
    for (int d = r4; d < 64; d += 4)
        WT[(size_t)d * EMBED + e0 + c] = f2bf(tile[c][d]);
}

// ---------------------------------------------------------------------------
// K1: proj only (transpose removed). Q = 0.125*(h*Wq+bq), K = h*Wk+bk.
// grid 512 (B * S/16), 256 thr, 16 s-rows/block, EC=128 per iter:
// 8 iters, 8 barriers, 8 MFMA + 4 ds_read_b128 per wave per iter.
// Double-buffered LDS; h prefetched DEPTH-2 (hides ~900cyc HBM latency),
// W-frags prefetched 1 iter ahead (L2-resident).
// ---------------------------------------------------------------------------
__global__ __launch_bounds__(256) void proj_kernel(
    const float* __restrict__ h, const u16* __restrict__ WqT, const u16* __restrict__ WkT,
    const float* __restrict__ bq, const float* __restrict__ bk,
    u16* __restrict__ Qbf, u16* __restrict__ Kbf)
{
    __shared__ u16 hs[2][16][136];   // 128 + 8 pad
    int b = blockIdx.x >> 7, s0 = (blockIdx.x & 127) * 16;
    int t = threadIdx.x, lane = t & 63, w = t >> 6;
    int l15 = lane & 15, quad = lane >> 4;
    int pj = w >> 1, nh = (w & 1) * 32;
    const float* hb = h + ((size_t)b * SEQ + s0) * EMBED;
    const u16* Wp = pj ? WkT : WqT;
    int r = t >> 4, c4 = (t & 15) * 4;   // staging: 16 rows x (16 f32x4 x 2 halves)

    f32x4 preA0 = *(const f32x4*)(hb + (size_t)r * EMBED + c4);
    f32x4 preA1 = *(const f32x4*)(hb + (size_t)r * EMBED + 64 + c4);
    f32x4 preB0 = *(const f32x4*)(hb + (size_t)r * EMBED + 128 + c4);
    f32x4 preB1 = *(const f32x4*)(hb + (size_t)r * EMBED + 192 + c4);
    f32x4 accA[2], accB[2];
    accA[0] = accA[1] = accB[0] = accB[1] = (f32x4){0.f, 0.f, 0.f, 0.f};

    const u16* Wrow0 = Wp + (size_t)(nh + l15) * EMBED;
    const u16* Wrow1 = Wp + (size_t)(nh + 16 + l15) * EMBED;

    short8 cw[8];
#pragma unroll
    for (int i = 0; i < 4; i++) {
        cw[i]     = *(const short8*)(Wrow0 + i * 32 + quad * 8);
        cw[4 + i] = *(const short8*)(Wrow1 + i * 32 + quad * 8);
    }

    for (int it = 0; it < 8; ++it) {
        int ec = it * 128, buf = it & 1;
        uint2 pk;
        pk.x = (u32)f2bf(preA0[0]) | ((u32)f2bf(preA0[1]) << 16);
        pk.y = (u32)f2bf(preA0[2]) | ((u32)f2bf(preA0[3]) << 16);
        *(uint2*)&hs[buf][r][c4] = pk;
        pk.x = (u32)f2bf(preA1[0]) | ((u32)f2bf(preA1[1]) << 16);
        pk.y = (u32)f2bf(preA1[2]) | ((u32)f2bf(preA1[3]) << 16);
        *(uint2*)&hs[buf][r][64 + c4] = pk;
        __syncthreads();

        preA0 = preB0; preA1 = preB1;
        if (it + 2 < 8) {
            preB0 = *(const f32x4*)(hb + (size_t)r * EMBED + ec + 256 + c4);
            preB1 = *(const f32x4*)(hb + (size_t)r * EMBED + ec + 320 + c4);
        }
        short8 nw[8];
#pragma unroll
        for (int i = 0; i < 8; i++) nw[i] = cw[i];
        if (it + 1 < 8) {
#pragma unroll
            for (int i = 0; i < 4; i++) {
                nw[i]     = *(const short8*)(Wrow0 + ec + 128 + i * 32 + quad * 8);
                nw[4 + i] = *(const short8*)(Wrow1 + ec + 128 + i * 32 + quad * 8);
            }
        }

        short8 a0 = *(const short8*)&hs[buf][l15][quad * 8];
        short8 a1 = *(const short8*)&hs[buf][l15][32 + quad * 8];
        short8 a2 = *(const short8*)&hs[buf][l15][64 + quad * 8];
        short8 a3 = *(const short8*)&hs[buf][l15][96 + quad * 8];
        // dependent accumulator reuses 4 apart
        accA[0] = __builtin_amdgcn_mfma_f32_16x16x32_bf16(a0, cw[0], accA[0], 0, 0, 0);
        accA[1] = __builtin_amdgcn_mfma_f32_16x16x32_bf16(a0, cw[4], accA[1], 0, 0, 0);
        accB[0] = __builtin_amdgcn_mfma_f32_16x16x32_bf16(a1, cw[1], accB[0], 0, 0, 0);
        accB[1] = __builtin_amdgcn_mfma_f32_16x16x32_bf16(a1, cw[5], accB[1], 0, 0, 0);
        accA[0] = __builtin_amdgcn_mfma_f32_16x16x32_bf16(a2, cw[2], accA[0], 0, 0, 0);
        accA[1] = __builtin_amdgcn_mfma_f32_16x16x32_bf16(a2, cw[6], accA[1], 0, 0, 0);
        accB[0] = __builtin_amdgcn_mfma_f32_16x16x32_bf16(a3, cw[3], accB[0], 0, 0, 0);
        accB[1] = __builtin_amdgcn_mfma_f32_16x16x32_bf16(a3, cw[7], accB[1], 0, 0, 0);
#pragma unroll
        for (int i = 0; i < 8; i++) cw[i] = nw[i];
    }

    const float* bias = pj ? bk : bq;
    float scale = pj ? 1.0f : 0.125f;
    u16* outp = pj ? Kbf : Qbf;
    float bv0 = bias[nh + l15], bv1 = bias[nh + 16 + l15];
#pragma unroll
    for (int rr = 0; rr < 4; rr++) {
        size_t row = (size_t)b * SEQ + s0 + quad * 4 + rr;
        outp[row * HDIM + nh + l15]      = f2bf((accA[0][rr] + accB[0][rr] + bv0) * scale);
        outp[row * HDIM + nh + 16 + l15] = f2bf((accA[1][rr] + accB[1][rr] + bv1) * scale);
    }
}

// ---------------------------------------------------------------------------
// K2: stats+weights SINGLE PASS. Block owns 16 k (k0) x all q; wave w owns
// q in [w*512,+512). K-frags loop-invariant. Per 32-q iter: 4 MFMA ->
// exp -> packed 8B stores of UNNORMALIZED exp(S) to Wmat + accumulate l.
// Ends writing invl[k] = 1/l[k]. grid (S/16, B) x 256.
// ---------------------------------------------------------------------------
__global__ __launch_bounds__(256) void sw_kernel(
    const u16* __restrict__ Qbf, const u16* __restrict__ Kbf,
    u16* __restrict__ Wmat, float* __restrict__ invl)
{
    __shared__ float sl[4][16];
    int b = blockIdx.y;
    int k0 = blockIdx.x * 16;
    int t = threadIdx.x, lane = t & 63, w = t >> 6;
    int l15 = lane & 15, quad = lane >> 4;
    const u16* Qb = Qbf + (size_t)b * SEQ * HDIM;
    const u16* Kb = Kbf + (size_t)b * SEQ * HDIM;
    u16* Wb = Wmat + (size_t)b * SEQ * SEQ;
    short8 kf0 = *(const short8*)(Kb + (size_t)(k0 + l15) * HDIM + quad * 8);
    short8 kf1 = *(const short8*)(Kb + (size_t)(k0 + l15) * HDIM + 32 + quad * 8);
    f32x4 lacc = {0.f, 0.f, 0.f, 0.f};
    int qs = w * 512;
    const u16* qpa = Qb + (size_t)(qs + l15) * HDIM;
    const u16* qpb = Qb + (size_t)(qs + 16 + l15) * HDIM;
    short8 cf0a = *(const short8*)(qpa + quad * 8);
    short8 cf1a = *(const short8*)(qpa + 32 + quad * 8);
    short8 cf0b = *(const short8*)(qpb + quad * 8);
    short8 cf1b = *(const short8*)(qpb + 32 + quad * 8);

    for (int q0 = qs; q0 < qs + 512; q0 += 32) {
        short8 nf0a = cf0a, nf1a = cf1a, nf0b = cf0b, nf1b = cf1b;
        if (q0 + 32 < qs + 512) {
            const u16* na = Qb + (size_t)(q0 + 32 + l15) * HDIM;
            const u16* nb = Qb + (size_t)(q0 + 48 + l15) * HDIM;
            nf0a = *(const short8*)(na + quad * 8);
            nf1a = *(const short8*)(na + 32 + quad * 8);
            nf0b = *(const short8*)(nb + quad * 8);
            nf1b = *(const short8*)(nb + 32 + quad * 8);
        }
        // A = K rows (m=k), B = Q rows (n=q): acc[r] = S[q_tile+l15][k0+quad*4+r]
        f32x4 aa = {0.f, 0.f, 0.f, 0.f}, ab = {0.f, 0.f, 0.f, 0.f};
        aa = __builtin_amdgcn_mfma_f32_16x16x32_bf16(kf0, cf0a, aa, 0, 0, 0);
        ab = __builtin_amdgcn_mfma_f32_16x16x32_bf16(kf0, cf0b, ab, 0, 0, 0);
        aa = __builtin_amdgcn_mfma_f32_16x16x32_bf16(kf1, cf1a, aa, 0, 0, 0);
        ab = __builtin_amdgcn_mfma_f32_16x16x32_bf16(kf1, cf1b, ab, 0, 0, 0);
        float e0 = __expf(aa[0]), e1 = __expf(aa[1]);
        float e2 = __expf(aa[2]), e3 = __expf(aa[3]);
        float g0 = __expf(ab[0]), g1 = __expf(ab[1]);
        float g2 = __expf(ab[2]), g3 = __expf(ab[3]);
        lacc[0] += e0 + g0; lacc[1] += e1 + g1;
        lacc[2] += e2 + g2; lacc[3] += e3 + g3;
        uint2 pa, pb;
        pa.x = (u32)f2bf(e0) | ((u32)f2bf(e1) << 16);
        pa.y = (u32)f2bf(e2) | ((u32)f2bf(e3) << 16);
        pb.x = (u32)f2bf(g0) | ((u32)f2bf(g1) << 16);
        pb.y = (u32)f2bf(g2) | ((u32)f2bf(g3) << 16);
        *(uint2*)(Wb + (size_t)(q0 + l15) * SEQ + k0 + quad * 4) = pa;
        *(uint2*)(Wb + (size_t)(q0 + 16 + l15) * SEQ + k0 + quad * 4) = pb;
        cf0a = nf0a; cf1a = nf1a; cf0b = nf0b; cf1b = nf1b;
    }
    // sum over l15 (q within tile): butterfly over lane bits 0..3
#pragma unroll
    for (int m = 1; m <= 8; m <<= 1) {
        lacc[0] += __shfl_xor(lacc[0], m, 64);
        lacc[1] += __shfl_xor(lacc[1], m, 64);
        lacc[2] += __shfl_xor(lacc[2], m, 64);
        lacc[3] += __shfl_xor(lacc[3], m, 64);
    }
    if (l15 == 0) {
        sl[w][quad * 4 + 0] = lacc[0];
        sl[w][quad * 4 + 1] = lacc[1];
        sl[w][quad * 4 + 2] = lacc[2];
        sl[w][quad * 4 + 3] = lacc[3];
    }
    __syncthreads();
    if (t < 16)
        invl[b * SEQ + k0 + t] =
            1.0f / ((sl[0][t] + sl[1][t]) + (sl[2][t] + sl[3][t]));
}

// ---------------------------------------------------------------------------
// K3: transpose + scale: hT[b][e][s] = bf16( h[b][s][e] * invl[b][s] ).
// 64x64 fp32 LDS tile, f32x4 global loads (coalesced), uint2 packed stores
// (4x fewer store instrs). LDS stride 65 keeps both phases ~conflict-free
// (2-way max = free). grid (S/64, E/64, B) x 256.
// ---------------------------------------------------------------------------
__global__ __launch_bounds__(256) void tscale_kernel(
    const float* __restrict__ h, const float* __restrict__ invl,
    u16* __restrict__ hT)
{
    __shared__ float tile[64][65];
    int b  = blockIdx.z;
    int s0 = blockIdx.x * 64, e0 = blockIdx.y * 64;
    int t = threadIdx.x;
    int r16 = t >> 4, c4 = (t & 15) * 4;
    const float* hb = h + (size_t)b * SEQ * EMBED;
#pragma unroll
    for (int rr = r16; rr < 64; rr += 16) {
        f32x4 v = *(const f32x4*)(hb + (size_t)(s0 + rr) * EMBED + e0 + c4);
        *(f32x4*)&tile[rr][c4] = v;
    }
    __syncthreads();
    f32x4 il4 = *(const f32x4*)(invl + b * SEQ + s0 + c4);   // 4 s-columns
    u16* hTb = hT + (size_t)b * EMBED * SEQ;
#pragma unroll
    for (int er = r16; er < 64; er += 16) {
        u16 p0 = f2bf(tile[c4 + 0][er] * il4[0]);
        u16 p1 = f2bf(tile[c4 + 1][er] * il4[1]);
        u16 p2 = f2bf(tile[c4 + 2][er] * il4[2]);
        u16 p3 = f2bf(tile[c4 + 3][er] * il4[3]);
        uint2 pk;
        pk.x = (u32)p0 | ((u32)p1 << 16);
        pk.y = (u32)p2 | ((u32)p3 << 16);
        *(uint2*)(hTb + (size_t)(e0 + er) * SEQ + s0 + c4) = pk;
    }
}

// ---------------------------------------------------------------------------
// K4: out[b][q][e] = sum_k Wmat[b][q][k] * hT[b][e][k]
// V4: low-overhead free-running tiles. BM=256 x BN=128, BK=64, 512 thr =
// 8 waves (2 kf-groups x 2M x 2N; wave tile 128x64 over its 32-wide k-half;
// acc[8][4]). 3-slot LDS ring (144KB), depth-2 staging, counted vmcnt(6).
// Main loop UNROLLED x3 -> slot bases are literals; all LDS read/dest byte
// offsets hoisted (loop-invariant); staging src pointers advance +64/tile.
// ONE barrier per K-tile (after vmcnt): waves free-run within a tile so
// one wave's MFMA cluster covers another's ds_reads/VALU; compiler emits
// fine-grained counted lgkmcnt between ds_read and MFMA (no asm drains).
// Correctness: reads of slot s for tile kt drain (consumed by MFMA) before
// each wave's tile-kt end barrier; staging into slot (kt+2)%3 = (kt-1)%3
// happens during kt, i.e. after ALL waves' tile-(kt-1) reads finished.
// Swizzle: phys chunk = logical ^ (row&7) on global source + ds_read side.
// Epilogue: kf=1 waves dump acc into retired ring LDS; kf=0 add + store.
// grid (8,8,4) = 256 blocks = 1/CU.
// ---------------------------------------------------------------------------
__global__ __launch_bounds__(512, 2) void out_gemm_kernel(
    const u16* __restrict__ Wmat, const u16* __restrict__ hT, float* __restrict__ out)
{
    __shared__ __align__(16) char smem[3 * 49152];   // 3 x (A 32KB + B 16KB)
    int b = blockIdx.z;
    int q0 = blockIdx.x * 256, e0 = blockIdx.y * 128;
    int t = threadIdx.x, lane = t & 63, w = t >> 6;
    int l15 = lane & 15, quad = lane >> 4;
    const u16* Wb  = Wmat + (size_t)b * SEQ * SEQ;
    const u16* hTb = hT + (size_t)b * EMBED * SEQ;
    int kf = w >> 2;                 // k-half group (0: k 0..31, 1: k 32..63)
    int wm = (w >> 1) & 1, wn = w & 1;
    int wq = wm * 128, we = wn * 64; // wave tile origin (128 x 64)

    f32x4 acc[8][4];
#pragma unroll
    for (int i = 0; i < 8; i++)
#pragma unroll
        for (int j = 0; j < 4; j++) acc[i][j] = (f32x4){0.f, 0.f, 0.f, 0.f};

    int st_rl = lane >> 3;            // row within 8-row group
    int st_pc = lane & 7;             // physical chunk at dest (= lane pattern)

    // ---- loop-invariant staging sources (advance +64 u16 per staged tile)
    const u16* gA[4];
    const u16* gB[2];
#pragma unroll
    for (int ld = 0; ld < 4; ld++) {
        int row = w * 32 + ld * 8 + st_rl;
        int cg  = st_pc ^ (row & 7);
        gA[ld] = Wb + (size_t)(q0 + row) * SEQ + cg * 8;
    }
#pragma unroll
    for (int ld = 0; ld < 2; ld++) {
        int row = w * 16 + ld * 8 + st_rl;
        int cg  = st_pc ^ (row & 7);
        gB[ld] = hTb + (size_t)(e0 + row) * SEQ + cg * 8;
    }
    // ---- loop-invariant LDS dest byte offsets within a slot
    int dA[4], dB[2];
#pragma unroll
    for (int ld = 0; ld < 4; ld++) dA[ld] = (w * 32 + ld * 8) * 128 + lane * 16;
#pragma unroll
    for (int ld = 0; ld < 2; ld++) dB[ld] = 32768 + (w * 16 + ld * 8) * 128 + lane * 16;
    // ---- loop-invariant LDS read byte offsets within a slot
    int offA[8], offB[4];
#pragma unroll
    for (int ii = 0; ii < 8; ii++) {
        int ra  = wq + ii * 16 + l15;
        int pca = (kf * 4 + quad) ^ (ra & 7);
        offA[ii] = ra * 128 + pca * 16;
    }
#pragma unroll
    for (int j = 0; j < 4; j++) {
        int rb  = we + j * 16 + l15;
        int pcb = (kf * 4 + quad) ^ (rb & 7);
        offB[j] = 32768 + rb * 128 + pcb * 16;
    }

#define STAGE_H1(si)                                                           \
    {                                                                          \
        gload_lds16(gA[0], (u16*)(smem + (si) * 49152 + dA[0]));               \
        gload_lds16(gA[1], (u16*)(smem + (si) * 49152 + dA[1]));               \
        gload_lds16(gB[0], (u16*)(smem + (si) * 49152 + dB[0]));               \
    }
#define STAGE_H2(si)                                                           \
    {                                                                          \
        gload_lds16(gA[2], (u16*)(smem + (si) * 49152 + dA[2]));               \
        gload_lds16(gA[3], (u16*)(smem + (si) * 49152 + dA[3]));               \
        gload_lds16(gB[1], (u16*)(smem + (si) * 49152 + dB[1]));               \
    }
#define ADV()                                                                  \
    {                                                                          \
        gA[0] += 64; gA[1] += 64; gA[2] += 64; gA[3] += 64;                    \
        gB[0] += 64; gB[1] += 64;                                              \
    }

#define MFMA16(i0)                                                             \
    {                                                                          \
        _Pragma("unroll")                                                      \
        for (int ii = 0; ii < 4; ii++)                                         \
            _Pragma("unroll")                                                  \
            for (int j = 0; j < 4; j++)                                        \
                acc[(i0) + ii][j] = __builtin_amdgcn_mfma_f32_16x16x32_bf16(   \
                    af[ii], bfr[j], acc[(i0) + ii][j], 0, 0, 0);               \
    }

    // TILE body: slot si (literal), optional staging of tile kt+2 into si2
    // = (si+2)%3, end-of-tile counted vmcnt + barrier.
#define TILE(si, si2, DO_STAGE, VMC)                                           \
    {                                                                          \
        const char* Sb = smem + (si) * 49152;                                  \
        short8 af[4], bfr[4];                                                  \
        _Pragma("unroll")                                                      \
        for (int ii = 0; ii < 4; ii++)                                         \
            af[ii] = *(const short8*)(Sb + offA[ii]);                          \
        _Pragma("unroll")                                                      \
        for (int j = 0; j < 4; j++)                                            \
            bfr[j] = *(const short8*)(Sb + offB[j]);                           \
        if (DO_STAGE) STAGE_H1(si2)                                            \
        __builtin_amdgcn_s_setprio(1);                                         \
        MFMA16(0)                                                              \
        __builtin_amdgcn_s_setprio(0);                                         \
        _Pragma("unroll")                                                      \
        for (int ii = 0; ii < 4; ii++)                                         \
            af[ii] = *(const short8*)(Sb + offA[4 + ii]);                      \
        if (DO_STAGE) { STAGE_H2(si2) ADV() }                                  \
        __builtin_amdgcn_s_setprio(1);                                         \
        MFMA16(4)                                                              \
        __builtin_amdgcn_s_setprio(0);                                         \
        if ((VMC) == 6) { asm volatile("s_waitcnt vmcnt(6)" ::: "memory"); }   \
        else if ((VMC) == 0) { asm volatile("s_waitcnt vmcnt(0)" ::: "memory"); } \
        __builtin_amdgcn_s_barrier();                                          \
    }

    // Prologue: stage tiles 0 (slot 0) and 1 (slot 1).
    STAGE_H1(0) STAGE_H2(0) ADV()
    STAGE_H1(1) STAGE_H2(1) ADV()
    asm volatile("s_waitcnt vmcnt(6)" ::: "memory");   // own tile-0 loads done
    __builtin_amdgcn_s_barrier();                      // published to all

    // Tiles 0..29: unrolled x3, staging tiles 2..31, vmcnt(6) each.
    for (int g = 0; g < 10; ++g) {
        TILE(0, 2, true, 6)
        TILE(1, 0, true, 6)
        TILE(2, 1, true, 6)
    }
    // Tile 30 (slot 0): no staging; drain remaining (tile 31's 6 loads).
    TILE(0, 2, false, 0)
    // Tile 31 (slot 1): no staging, no vmcnt; end barrier guards smem reuse.
    TILE(1, 0, false, -1)
#undef TILE
#undef STAGE_H1
#undef STAGE_H2
#undef ADV
#undef MFMA16

    // Epilogue: combine kf=1 partials into kf=0 waves via ring LDS.
    // Region per wave-pair (w&3): 32KB = 32 frags x 64 lanes x 16B.
    float* red = (float*)smem;
    if (w >= 4) {
        float* reg = red + (size_t)(w & 3) * 8192;
#pragma unroll
        for (int i = 0; i < 8; i++)
#pragma unroll
            for (int j = 0; j < 4; j++)
                *(f32x4*)(reg + ((i * 4 + j) * 64 + lane) * 4) = acc[i][j];
    }
    __syncthreads();
    if (w < 4) {
        float* reg = red + (size_t)w * 8192;
        float* outb = out + (size_t)b * SEQ * EMBED;
#pragma unroll
        for (int i = 0; i < 8; i++)
#pragma unroll
            for (int j = 0; j < 4; j++) {
                f32x4 o = *(const f32x4*)(reg + ((i * 4 + j) * 64 + lane) * 4);
                o += acc[i][j];
#pragma unroll
                for (int r = 0; r < 4; r++)
                    outb[(size_t)(q0 + wq + i * 16 + quad * 4 + r) * EMBED
                         + e0 + we + j * 16 + l15] = o[r];
            }
    }
}

// ---------------------------------------------------------------------------
extern "C" void kernel_launch(void* const* d_in, const int* in_sizes, int n_in,
                              void* d_out, int out_size, void* d_ws, size_t ws_size,
                              hipStream_t stream) {
    (void)in_sizes; (void)n_in; (void)out_size; (void)ws_size;
    const float* h  = (const float*)d_in[0];
    const float* Wq = (const float*)d_in[1];
    const float* bq = (const float*)d_in[2];
    const float* Wk = (const float*)d_in[3];
    const float* bk = (const float*)d_in[4];
    // d_in[5], d_in[6] (Wv, bv) are dead in the reference.
    float* out = (float*)d_out;

    char* ws = (char*)d_ws;
    u16*   Qbf  = (u16*)(ws);                                  // 1 MB
    u16*   Kbf  = (u16*)(ws + (1ull << 20));                   // 1 MB
    u16*   hT   = (u16*)(ws + (2ull << 20));                   // 16 MB
    float* invl = (float*)(ws + (18ull << 20));                // 32 KB
    u16*   WqT  = (u16*)(ws + (18ull << 20) + (128ull << 10)); // 128 KB
    u16*   WkT  = (u16*)(ws + (18ull << 20) + (256ull << 10)); // 128 KB
    u16*   Wmat = (u16*)(ws + (19ull << 20));                  // 32 MB (total ~51 MB)

    hipLaunchKernelGGL(wt_kernel, dim3(16, 2), dim3(256), 0, stream, Wq, Wk, WqT, WkT);
    hipLaunchKernelGGL(proj_kernel, dim3(512), dim3(256), 0, stream,
                       h, WqT, WkT, bq, bk, Qbf, Kbf);
    hipLaunchKernelGGL(sw_kernel, dim3(128, 4), dim3(256), 0, stream,
                       Qbf, Kbf, Wmat, invl);
    hipLaunchKernelGGL(tscale_kernel, dim3(32, 16, 4), dim3(256), 0, stream,
                       h, invl, hT);
    hipLaunchKernelGGL(out_gemm_kernel, dim3(8, 8, 4), dim3(512), 0, stream,
                       Wmat, hT, out);
}